// Round 1
// baseline (955.459 us; speedup 1.0000x reference)
//
#include <hip/hip_runtime.h>
#include <math.h>

#define B_    2
#define TU_   1024
#define D_    80
#define H_    8
#define DH_   10
#define FFN_  2048
#define SEG_  32
#define RC_   8
#define LC_   50
#define NSEG_ 32
#define RCT_  256
#define L_    1280
#define NLAYERS_ 4
#define OUTD_ 768
#define EPS_  1e-5f
#define SCALE_ 0.31622776601683794f   // 10^-0.5
#define NR_   (B_*L_)                 // 2560 rows

// ---------------- gather x0 = [r ; u] ----------------
__global__ void k_build_x(const float* __restrict__ mel, float* __restrict__ x) {
  int idx = blockIdx.x * blockDim.x + threadIdx.x;
  if (idx >= B_*L_*D_) return;
  int d = idx % D_;
  int i = (idx / D_) % L_;
  int b = idx / (D_*L_);
  int srow;
  if (i < RCT_) { int seg = i / RC_, j = i % RC_; srow = (seg+1)*SEG_ + j; }  // last seg: 32*32+j = 1024+j, matches
  else          { srow = i - RCT_; }
  x[idx] = mel[(b*(TU_+RC_) + srow)*D_ + d];
}

// ---------------- LayerNorm over D=80 (population variance) ----------------
__global__ __launch_bounds__(128) void k_ln(const float* __restrict__ in, const float* __restrict__ w,
    const float* __restrict__ b, float* __restrict__ out) {
  int row = blockIdx.x;
  int tid = threadIdx.x;
  __shared__ float s1[128], s2[128];
  float v = (tid < D_) ? in[row*D_ + tid] : 0.f;
  s1[tid] = v; s2[tid] = v*v;
  __syncthreads();
  for (int off = 64; off > 0; off >>= 1) {
    if (tid < off) { s1[tid] += s1[tid+off]; s2[tid] += s2[tid+off]; }
    __syncthreads();
  }
  float mean = s1[0] * (1.f/D_);
  float var  = s2[0] * (1.f/D_) - mean*mean;
  float inv  = rsqrtf(var + EPS_);
  if (tid < D_) out[row*D_ + tid] = (v - mean) * inv * w[tid] + b[tid];
}

// ---------------- QKV projection (row-block, K=80) ----------------
__global__ __launch_bounds__(256) void k_qkv(const float* __restrict__ xn,
    const float* __restrict__ wq, const float* __restrict__ bq,
    const float* __restrict__ wkv, const float* __restrict__ bkv,
    float* __restrict__ q, float* __restrict__ kv) {
  int row = blockIdx.x, tid = threadIdx.x;
  __shared__ float xr[D_];
  if (tid < D_) xr[tid] = xn[row*D_ + tid];
  __syncthreads();
  if (tid < D_) {
    float acc = 0.f;
    #pragma unroll 8
    for (int k = 0; k < D_; ++k) acc += xr[k] * wq[k*D_ + tid];
    q[row*D_ + tid] = (acc + bq[tid]) * SCALE_;
  } else if (tid < D_ + 2*D_) {
    int c = tid - D_;
    float acc = 0.f;
    #pragma unroll 8
    for (int k = 0; k < D_; ++k) acc += xr[k] * wkv[k*2*D_ + c];
    kv[row*2*D_ + c] = acc + bkv[c];
  }
}

// ---------------- block-sparse attention: one block per (segment, batch) ----------------
// queries: 8 r-rows + 32 u-rows; keys: 8 r-rows + [max(i*32-50,0), (i+1)*32) u-rows (<=90)
__global__ __launch_bounds__(320) void k_attn(const float* __restrict__ q,
    const float* __restrict__ kv, float* __restrict__ att) {
  int seg = blockIdx.x, b = blockIdx.y;
  int tid = threadIdx.x;
  int seg_start = seg*SEG_ - LC_; if (seg_start < 0) seg_start = 0;
  int seg_end = (seg+1)*SEG_;
  int kc = RC_ + (seg_end - seg_start);          // <= 90
  __shared__ float Ksh[90][D_];
  __shared__ float Vsh[90][D_];
  for (int idx = tid; idx < kc*2*D_; idx += 320) {
    int kk = idx / (2*D_), c = idx % (2*D_);
    int krow = (kk < RC_) ? seg*RC_ + kk : RCT_ + seg_start + (kk - RC_);
    float v = kv[(b*L_ + krow)*2*D_ + c];
    if (c < D_) Ksh[kk][c] = v; else Vsh[kk][c - D_] = v;
  }
  __syncthreads();
  int qi = tid >> 3, h = tid & 7;                // 40 queries x 8 heads = 320 threads
  int qrow = (qi < RC_) ? seg*RC_ + qi : RCT_ + seg*SEG_ + (qi - RC_);
  float qv[DH_];
  #pragma unroll
  for (int d = 0; d < DH_; ++d) qv[d] = q[(b*L_ + qrow)*D_ + h*DH_ + d];
  float m = -INFINITY, l = 0.f, acc[DH_] = {};
  for (int kk = 0; kk < kc; ++kk) {
    float s = 0.f;
    #pragma unroll
    for (int d = 0; d < DH_; ++d) s += qv[d] * Ksh[kk][h*DH_ + d];
    float mn = fmaxf(m, s);
    float corr = expf(m - mn);
    float p = expf(s - mn);
    l = l*corr + p;
    #pragma unroll
    for (int d = 0; d < DH_; ++d) acc[d] = acc[d]*corr + p*Vsh[kk][h*DH_ + d];
    m = mn;
  }
  float invl = 1.f / l;
  #pragma unroll
  for (int d = 0; d < DH_; ++d) att[(b*L_ + qrow)*D_ + h*DH_ + d] = acc[d] * invl;
}

// ---------------- out-proj + residual ----------------
__global__ __launch_bounds__(128) void k_wo_res(const float* __restrict__ att,
    const float* __restrict__ wo, const float* __restrict__ bo,
    const float* __restrict__ x, float* __restrict__ res) {
  int row = blockIdx.x, tid = threadIdx.x;
  __shared__ float ar[D_];
  if (tid < D_) ar[tid] = att[row*D_ + tid];
  __syncthreads();
  if (tid < D_) {
    float acc = 0.f;
    #pragma unroll 8
    for (int k = 0; k < D_; ++k) acc += ar[k] * wo[k*D_ + tid];
    res[row*D_ + tid] = acc + bo[tid] + x[row*D_ + tid];
  }
}

// ---------------- FFN1: (2560x80)@(80x2048) + bias, relu. Tiled 64x64, full-K in LDS ----------------
__global__ __launch_bounds__(256) void k_ffn1(const float* __restrict__ hn,
    const float* __restrict__ w1, const float* __restrict__ b1, float* __restrict__ ff1) {
  __shared__ float As[64][D_];
  __shared__ float Bs[D_][65];
  int bm = blockIdx.x*64, bn = blockIdx.y*64;
  int tid = threadIdx.x;
  for (int idx = tid; idx < 64*D_; idx += 256) { int r = idx/D_, c = idx%D_; As[r][c] = hn[(bm+r)*D_ + c]; }
  for (int idx = tid; idx < D_*64; idx += 256) { int r = idx/64, c = idx%64; Bs[r][c] = w1[r*FFN_ + bn + c]; }
  __syncthreads();
  int tx = tid & 15, ty = tid >> 4;
  float acc[4][4] = {};
  for (int k = 0; k < D_; ++k) {
    float a[4], bb[4];
    #pragma unroll
    for (int i = 0; i < 4; ++i) a[i] = As[ty*4+i][k];
    #pragma unroll
    for (int j = 0; j < 4; ++j) bb[j] = Bs[k][tx*4+j];
    #pragma unroll
    for (int i = 0; i < 4; ++i)
      #pragma unroll
      for (int j = 0; j < 4; ++j) acc[i][j] += a[i]*bb[j];
  }
  #pragma unroll
  for (int i = 0; i < 4; ++i)
    #pragma unroll
    for (int j = 0; j < 4; ++j) {
      int r = bm + ty*4+i, c = bn + tx*4+j;
      ff1[r*FFN_ + c] = fmaxf(acc[i][j] + b1[c], 0.f);
    }
}

// ---------------- FFN2: (2560x2048)@(2048x80) + bias + residual. 16 rows x 80 cols per block ----------------
__global__ __launch_bounds__(256) void k_ffn2(const float* __restrict__ ff1,
    const float* __restrict__ w2, const float* __restrict__ b2,
    const float* __restrict__ res, float* __restrict__ res2) {
  __shared__ float As[16][65];
  __shared__ float Bs[64][D_];
  int bm = blockIdx.x*16;
  int tid = threadIdx.x;
  int tx = tid & 15, ty = tid >> 4;   // ty = row (16), tx+16*j = col (80)
  float acc[5] = {};
  for (int k0 = 0; k0 < FFN_; k0 += 64) {
    for (int idx = tid; idx < 16*64; idx += 256) { int r = idx/64, c = idx%64; As[r][c] = ff1[(bm+r)*FFN_ + k0 + c]; }
    for (int idx = tid; idx < 64*D_; idx += 256) { int r = idx/D_, c = idx%D_; Bs[r][c] = w2[(k0+r)*D_ + c]; }
    __syncthreads();
    #pragma unroll 8
    for (int k = 0; k < 64; ++k) {
      float a = As[ty][k];
      #pragma unroll
      for (int j = 0; j < 5; ++j) acc[j] += a * Bs[k][tx + 16*j];
    }
    __syncthreads();
  }
  int row = bm + ty;
  #pragma unroll
  for (int j = 0; j < 5; ++j) {
    int c = tx + 16*j;
    res2[row*D_ + c] = acc[j] + b2[c] + res[row*D_ + c];
  }
}

// ---------------- final projection u@(80x768)+pb ----------------
__global__ __launch_bounds__(256) void k_proj(const float* __restrict__ x,
    const float* __restrict__ pw, const float* __restrict__ pb, float* __restrict__ out) {
  int row = blockIdx.x;            // 0..2047 = b*1024+t
  int tid = threadIdx.x;
  int b = row >> 10, t = row & 1023;
  int xrow = b*L_ + RCT_ + t;
  __shared__ float xr[D_];
  if (tid < D_) xr[tid] = x[xrow*D_ + tid];
  __syncthreads();
  for (int c = tid; c < OUTD_; c += 256) {
    float acc = 0.f;
    #pragma unroll 8
    for (int k = 0; k < D_; ++k) acc += xr[k] * pw[k*OUTD_ + c];
    out[row*OUTD_ + c] = acc + pb[c];
  }
}

__global__ void k_len(const int* __restrict__ len, float* __restrict__ out) {
  int t = threadIdx.x;
  if (t < B_) out[t] = (float)len[t];
}

extern "C" void kernel_launch(void* const* d_in, const int* in_sizes, int n_in,
                              void* d_out, int out_size, void* d_ws, size_t ws_size,
                              hipStream_t stream) {
  const float* mel     = (const float*)d_in[0];
  const int*   lengths = (const int*)  d_in[1];
  const float* ln_in_w = (const float*)d_in[2];
  const float* ln_in_b = (const float*)d_in[3];
  const float* wq      = (const float*)d_in[4];
  const float* bq      = (const float*)d_in[5];
  const float* wkv     = (const float*)d_in[6];
  const float* bkv     = (const float*)d_in[7];
  const float* wo      = (const float*)d_in[8];
  const float* bo      = (const float*)d_in[9];
  const float* ln_ff_w = (const float*)d_in[10];
  const float* ln_ff_b = (const float*)d_in[11];
  const float* w1      = (const float*)d_in[12];
  const float* b1      = (const float*)d_in[13];
  const float* w2      = (const float*)d_in[14];
  const float* b2      = (const float*)d_in[15];
  const float* ln_o_w  = (const float*)d_in[16];
  const float* ln_o_b  = (const float*)d_in[17];
  const float* pw      = (const float*)d_in[18];
  const float* pb      = (const float*)d_in[19];
  float* out = (float*)d_out;

  float* ws = (float*)d_ws;
  float* x    = ws; ws += NR_*D_;
  float* xn   = ws; ws += NR_*D_;
  float* qb   = ws; ws += NR_*D_;
  float* kvb  = ws; ws += NR_*2*D_;
  float* attb = ws; ws += NR_*D_;
  float* resb = ws; ws += NR_*D_;
  float* hnb  = ws; ws += NR_*D_;
  float* ff1b = ws; ws += NR_*FFN_;
  float* res2b= ws; ws += NR_*D_;
  // total ~28.3 MB of d_ws

  k_build_x<<<(B_*L_*D_ + 255)/256, 256, 0, stream>>>(mel, x);

  for (int l = 0; l < NLAYERS_; ++l) {
    k_ln  <<<NR_, 128, 0, stream>>>(x, ln_in_w + l*D_, ln_in_b + l*D_, xn);
    k_qkv <<<NR_, 256, 0, stream>>>(xn, wq + l*D_*D_, bq + l*D_,
                                    wkv + l*D_*2*D_, bkv + l*2*D_, qb, kvb);
    k_attn<<<dim3(NSEG_, B_), 320, 0, stream>>>(qb, kvb, attb);
    k_wo_res<<<NR_, 128, 0, stream>>>(attb, wo + l*D_*D_, bo + l*D_, x, resb);
    k_ln  <<<NR_, 128, 0, stream>>>(resb, ln_ff_w + l*D_, ln_ff_b + l*D_, hnb);
    k_ffn1<<<dim3(NR_/64, FFN_/64), 256, 0, stream>>>(hnb, w1 + l*D_*FFN_, b1 + l*FFN_, ff1b);
    k_ffn2<<<NR_/16, 256, 0, stream>>>(ff1b, w2 + l*FFN_*D_, b2 + l*D_, resb, res2b);
    k_ln  <<<NR_, 128, 0, stream>>>(res2b, ln_o_w + l*D_, ln_o_b + l*D_, x);  // x <- next layer input
  }

  k_proj<<<B_*TU_, 256, 0, stream>>>(x, pw, pb, out);
  k_len <<<1, 64, 0, stream>>>(lengths, out + B_*TU_*OUTD_);
}

// Round 2
// 370.334 us; speedup vs baseline: 2.5800x; 2.5800x over previous
//
#include <hip/hip_runtime.h>
#include <math.h>

#define B_    2
#define TU_   1024
#define D_    80
#define H_    8
#define DH_   10
#define FFN_  2048
#define SEG_  32
#define RC_   8
#define LC_   50
#define NSEG_ 32
#define RCT_  256
#define L_    1280
#define NLAYERS_ 4
#define OUTD_ 768
#define EPS_  1e-5f
#define SCALE_ 0.31622776601683794f   // 10^-0.5
#define NR_   (B_*L_)                 // 2560 rows
#define KP_   96                      // K=80 padded to 96 for MFMA
#define KSPLIT_ 8
#define KCH_  (FFN_/KSPLIT_)          // 256

typedef __attribute__((ext_vector_type(8))) short bf16x8;
typedef __attribute__((ext_vector_type(4))) float f32x4;
typedef unsigned short ushort_t;

__device__ inline ushort_t f2bf(float f) {
  union { float f; unsigned u; } x; x.f = f;
  unsigned r = x.u + 0x7fffu + ((x.u >> 16) & 1u);   // RNE
  return (ushort_t)(r >> 16);
}

// ---------------- gather x0 = [r ; u] ----------------
__global__ void k_build_x(const float* __restrict__ mel, float* __restrict__ x) {
  int idx = blockIdx.x * blockDim.x + threadIdx.x;
  if (idx >= B_*L_*D_) return;
  int d = idx % D_;
  int i = (idx / D_) % L_;
  int b = idx / (D_*L_);
  int srow;
  if (i < RCT_) { int seg = i / RC_, j = i % RC_; srow = (seg+1)*SEG_ + j; }
  else          { srow = i - RCT_; }
  x[idx] = mel[(b*(TU_+RC_) + srow)*D_ + d];
}

// ---------------- weight conversion (once) ----------------
__global__ void k_w1t(const float* __restrict__ w1, ushort_t* __restrict__ w1T) {
  int idx = blockIdx.x * blockDim.x + threadIdx.x;
  if (idx >= NLAYERS_*FFN_*KP_) return;
  int k = idx % KP_;
  int n = (idx / KP_) % FFN_;
  int l = idx / (KP_*FFN_);
  float v = (k < D_) ? w1[(l*D_ + k)*FFN_ + n] : 0.f;
  w1T[idx] = f2bf(v);
}
__global__ void k_w2t(const float* __restrict__ w2, ushort_t* __restrict__ w2T) {
  int idx = blockIdx.x * blockDim.x + threadIdx.x;
  if (idx >= NLAYERS_*D_*FFN_) return;
  int k = idx % FFN_;
  int n = (idx / FFN_) % D_;
  int l = idx / (FFN_*D_);
  w2T[idx] = f2bf(w2[(l*FFN_ + k)*D_ + n]);
}

// ---------------- LayerNorm over D=80 (fp32 out) ----------------
__global__ __launch_bounds__(128) void k_ln(const float* __restrict__ in, const float* __restrict__ w,
    const float* __restrict__ b, float* __restrict__ out) {
  int row = blockIdx.x;
  int tid = threadIdx.x;
  __shared__ float s1[128], s2[128];
  float v = (tid < D_) ? in[row*D_ + tid] : 0.f;
  s1[tid] = v; s2[tid] = v*v;
  __syncthreads();
  for (int off = 64; off > 0; off >>= 1) {
    if (tid < off) { s1[tid] += s1[tid+off]; s2[tid] += s2[tid+off]; }
    __syncthreads();
  }
  float mean = s1[0] * (1.f/D_);
  float var  = s2[0] * (1.f/D_) - mean*mean;
  float inv  = rsqrtf(var + EPS_);
  if (tid < D_) out[row*D_ + tid] = (v - mean) * inv * w[tid] + b[tid];
}

// ---------------- LayerNorm -> bf16 padded [NR][96] ----------------
__global__ __launch_bounds__(128) void k_ln_bf(const float* __restrict__ in, const float* __restrict__ w,
    const float* __restrict__ b, ushort_t* __restrict__ out) {
  int row = blockIdx.x;
  int tid = threadIdx.x;
  __shared__ float s1[128], s2[128];
  float v = (tid < D_) ? in[row*D_ + tid] : 0.f;
  s1[tid] = v; s2[tid] = v*v;
  __syncthreads();
  for (int off = 64; off > 0; off >>= 1) {
    if (tid < off) { s1[tid] += s1[tid+off]; s2[tid] += s2[tid+off]; }
    __syncthreads();
  }
  float mean = s1[0] * (1.f/D_);
  float var  = s2[0] * (1.f/D_) - mean*mean;
  float inv  = rsqrtf(var + EPS_);
  if (tid < D_)      out[row*KP_ + tid] = f2bf((v - mean) * inv * w[tid] + b[tid]);
  else if (tid < KP_) out[row*KP_ + tid] = 0;
}

// ---------------- QKV projection (row-block, K=80) ----------------
__global__ __launch_bounds__(256) void k_qkv(const float* __restrict__ xn,
    const float* __restrict__ wq, const float* __restrict__ bq,
    const float* __restrict__ wkv, const float* __restrict__ bkv,
    float* __restrict__ q, float* __restrict__ kv) {
  int row = blockIdx.x, tid = threadIdx.x;
  __shared__ float xr[D_];
  if (tid < D_) xr[tid] = xn[row*D_ + tid];
  __syncthreads();
  if (tid < D_) {
    float acc = 0.f;
    #pragma unroll 8
    for (int k = 0; k < D_; ++k) acc += xr[k] * wq[k*D_ + tid];
    q[row*D_ + tid] = (acc + bq[tid]) * SCALE_;
  } else if (tid < D_ + 2*D_) {
    int c = tid - D_;
    float acc = 0.f;
    #pragma unroll 8
    for (int k = 0; k < D_; ++k) acc += xr[k] * wkv[k*2*D_ + c];
    kv[row*2*D_ + c] = acc + bkv[c];
  }
}

// ---------------- block-sparse attention ----------------
__global__ __launch_bounds__(320) void k_attn(const float* __restrict__ q,
    const float* __restrict__ kv, float* __restrict__ att) {
  int seg = blockIdx.x, b = blockIdx.y;
  int tid = threadIdx.x;
  int seg_start = seg*SEG_ - LC_; if (seg_start < 0) seg_start = 0;
  int seg_end = (seg+1)*SEG_;
  int kc = RC_ + (seg_end - seg_start);          // <= 90
  __shared__ float Ksh[90][D_];
  __shared__ float Vsh[90][D_];
  for (int idx = tid; idx < kc*2*D_; idx += 320) {
    int kk = idx / (2*D_), c = idx % (2*D_);
    int krow = (kk < RC_) ? seg*RC_ + kk : RCT_ + seg_start + (kk - RC_);
    float v = kv[(b*L_ + krow)*2*D_ + c];
    if (c < D_) Ksh[kk][c] = v; else Vsh[kk][c - D_] = v;
  }
  __syncthreads();
  int qi = tid >> 3, h = tid & 7;                // 40 queries x 8 heads
  int qrow = (qi < RC_) ? seg*RC_ + qi : RCT_ + seg*SEG_ + (qi - RC_);
  float qv[DH_];
  #pragma unroll
  for (int d = 0; d < DH_; ++d) qv[d] = q[(b*L_ + qrow)*D_ + h*DH_ + d];
  float m = -INFINITY, l = 0.f, acc[DH_] = {};
  for (int kk = 0; kk < kc; ++kk) {
    float s = 0.f;
    #pragma unroll
    for (int d = 0; d < DH_; ++d) s += qv[d] * Ksh[kk][h*DH_ + d];
    float mn = fmaxf(m, s);
    float corr = expf(m - mn);
    float p = expf(s - mn);
    l = l*corr + p;
    #pragma unroll
    for (int d = 0; d < DH_; ++d) acc[d] = acc[d]*corr + p*Vsh[kk][h*DH_ + d];
    m = mn;
  }
  float invl = 1.f / l;
  #pragma unroll
  for (int d = 0; d < DH_; ++d) att[(b*L_ + qrow)*D_ + h*DH_ + d] = acc[d] * invl;
}

// ---------------- out-proj + residual ----------------
__global__ __launch_bounds__(128) void k_wo_res(const float* __restrict__ att,
    const float* __restrict__ wo, const float* __restrict__ bo,
    const float* __restrict__ x, float* __restrict__ res) {
  int row = blockIdx.x, tid = threadIdx.x;
  __shared__ float ar[D_];
  if (tid < D_) ar[tid] = att[row*D_ + tid];
  __syncthreads();
  if (tid < D_) {
    float acc = 0.f;
    #pragma unroll 8
    for (int k = 0; k < D_; ++k) acc += ar[k] * wo[k*D_ + tid];
    res[row*D_ + tid] = acc + bo[tid] + x[row*D_ + tid];
  }
}

// ---------------- FFN1 MFMA: [2560x96]bf16 @ [96x2048]bf16 -> bf16, bias+relu ----------------
// grid (40, 16), block 256 (4 waves). wave computes 64x32; frags 4M x 2N, K unrolled (3 steps).
__global__ __launch_bounds__(256) void k_ffn1_mfma(const ushort_t* __restrict__ hnb,
    const ushort_t* __restrict__ w1T, const float* __restrict__ b1, ushort_t* __restrict__ ff1) {
  int wv = threadIdx.x >> 6, lane = threadIdx.x & 63;
  int bm = blockIdx.x * 64;
  int bn = blockIdx.y * 128 + wv*32;
  int r = lane & 15, g = lane >> 4;
  f32x4 acc[4][2] = {};
  const ushort_t* Ab = hnb + (bm + r)*KP_ + g*8;
  const ushort_t* Bb = w1T + (bn + r)*KP_ + g*8;
  #pragma unroll
  for (int ks = 0; ks < KP_; ks += 32) {
    bf16x8 a[4], bfr[2];
    #pragma unroll
    for (int mf = 0; mf < 4; ++mf) a[mf]   = *(const bf16x8*)(Ab + mf*16*KP_ + ks);
    #pragma unroll
    for (int nf = 0; nf < 2; ++nf) bfr[nf] = *(const bf16x8*)(Bb + nf*16*KP_ + ks);
    #pragma unroll
    for (int mf = 0; mf < 4; ++mf)
      #pragma unroll
      for (int nf = 0; nf < 2; ++nf)
        acc[mf][nf] = __builtin_amdgcn_mfma_f32_16x16x32_bf16(a[mf], bfr[nf], acc[mf][nf], 0, 0, 0);
  }
  #pragma unroll
  for (int mf = 0; mf < 4; ++mf)
    #pragma unroll
    for (int nf = 0; nf < 2; ++nf) {
      int col = bn + nf*16 + r;
      float bc = b1[col];
      #pragma unroll
      for (int rr = 0; rr < 4; ++rr) {
        int row = bm + mf*16 + g*4 + rr;
        float v = acc[mf][nf][rr] + bc;
        ff1[row*FFN_ + col] = f2bf(fmaxf(v, 0.f));
      }
    }
}

// ---------------- FFN2 MFMA: [2560x2048]bf16 @ [2048x80]bf16 -> fp32 partials (K split 8) ----------------
// grid (80, 8), block 64 (1 wave). wave computes 32x80 over K-chunk 256; frags 2M x 5N.
__global__ __launch_bounds__(64) void k_ffn2_mfma(const ushort_t* __restrict__ ff1,
    const ushort_t* __restrict__ w2T, float* __restrict__ part) {
  int bm = blockIdx.x * 32;
  int kc = blockIdx.y;
  int lane = threadIdx.x;
  int r = lane & 15, g = lane >> 4;
  f32x4 acc[2][5] = {};
  const ushort_t* Ab = ff1 + (bm + r)*FFN_ + kc*KCH_ + g*8;
  const ushort_t* Bb = w2T + r*FFN_ + kc*KCH_ + g*8;
  #pragma unroll
  for (int ks = 0; ks < KCH_; ks += 32) {
    bf16x8 a[2], bfr[5];
    #pragma unroll
    for (int nf = 0; nf < 5; ++nf) bfr[nf] = *(const bf16x8*)(Bb + nf*16*FFN_ + ks);
    #pragma unroll
    for (int mf = 0; mf < 2; ++mf) a[mf]   = *(const bf16x8*)(Ab + mf*16*FFN_ + ks);
    #pragma unroll
    for (int mf = 0; mf < 2; ++mf)
      #pragma unroll
      for (int nf = 0; nf < 5; ++nf)
        acc[mf][nf] = __builtin_amdgcn_mfma_f32_16x16x32_bf16(a[mf], bfr[nf], acc[mf][nf], 0, 0, 0);
  }
  float* pbase = part + (size_t)kc*NR_*D_ + (size_t)bm*D_;
  #pragma unroll
  for (int mf = 0; mf < 2; ++mf)
    #pragma unroll
    for (int nf = 0; nf < 5; ++nf)
      #pragma unroll
      for (int rr = 0; rr < 4; ++rr) {
        int row = mf*16 + g*4 + rr;
        int col = nf*16 + r;
        pbase[row*D_ + col] = acc[mf][nf][rr];
      }
}

// ---------------- FFN2 reduce + bias + residual + LayerNorm_out -> x ----------------
__global__ __launch_bounds__(128) void k_ffn2_reduce_ln(const float* __restrict__ part,
    const float* __restrict__ b2, const float* __restrict__ res,
    const float* __restrict__ w, const float* __restrict__ b, float* __restrict__ xout) {
  int row = blockIdx.x, tid = threadIdx.x;
  __shared__ float s1[128], s2[128];
  float v = 0.f;
  if (tid < D_) {
    v = b2[tid] + res[row*D_ + tid];
    #pragma unroll
    for (int c = 0; c < KSPLIT_; ++c) v += part[((size_t)c*NR_ + row)*D_ + tid];
  }
  s1[tid] = v; s2[tid] = v*v;
  __syncthreads();
  for (int off = 64; off > 0; off >>= 1) {
    if (tid < off) { s1[tid] += s1[tid+off]; s2[tid] += s2[tid+off]; }
    __syncthreads();
  }
  float mean = s1[0] * (1.f/D_);
  float var  = s2[0] * (1.f/D_) - mean*mean;
  float inv  = rsqrtf(var + EPS_);
  if (tid < D_) xout[row*D_ + tid] = (v - mean) * inv * w[tid] + b[tid];
}

// ---------------- final projection u@(80x768)+pb ----------------
__global__ __launch_bounds__(256) void k_proj(const float* __restrict__ x,
    const float* __restrict__ pw, const float* __restrict__ pb, float* __restrict__ out) {
  int row = blockIdx.x;            // 0..2047 = b*1024+t
  int tid = threadIdx.x;
  int b = row >> 10, t = row & 1023;
  int xrow = b*L_ + RCT_ + t;
  __shared__ float xr[D_];
  if (tid < D_) xr[tid] = x[xrow*D_ + tid];
  __syncthreads();
  for (int c = tid; c < OUTD_; c += 256) {
    float acc = 0.f;
    #pragma unroll 8
    for (int k = 0; k < D_; ++k) acc += xr[k] * pw[k*OUTD_ + c];
    out[row*OUTD_ + c] = acc + pb[c];
  }
}

__global__ void k_len(const int* __restrict__ len, float* __restrict__ out) {
  int t = threadIdx.x;
  if (t < B_) out[t] = (float)len[t];
}

extern "C" void kernel_launch(void* const* d_in, const int* in_sizes, int n_in,
                              void* d_out, int out_size, void* d_ws, size_t ws_size,
                              hipStream_t stream) {
  const float* mel     = (const float*)d_in[0];
  const int*   lengths = (const int*)  d_in[1];
  const float* ln_in_w = (const float*)d_in[2];
  const float* ln_in_b = (const float*)d_in[3];
  const float* wq      = (const float*)d_in[4];
  const float* bq      = (const float*)d_in[5];
  const float* wkv     = (const float*)d_in[6];
  const float* bkv     = (const float*)d_in[7];
  const float* wo      = (const float*)d_in[8];
  const float* bo      = (const float*)d_in[9];
  const float* ln_ff_w = (const float*)d_in[10];
  const float* ln_ff_b = (const float*)d_in[11];
  const float* w1      = (const float*)d_in[12];
  const float* b1      = (const float*)d_in[13];
  const float* w2      = (const float*)d_in[14];
  const float* b2      = (const float*)d_in[15];
  const float* ln_o_w  = (const float*)d_in[16];
  const float* ln_o_b  = (const float*)d_in[17];
  const float* pw      = (const float*)d_in[18];
  const float* pb      = (const float*)d_in[19];
  float* out = (float*)d_out;

  // ---- workspace layout (fp32 first, then bf16; all 16B aligned) ----
  float* ws = (float*)d_ws;
  float* x     = ws; ws += NR_*D_;
  float* xn    = ws; ws += NR_*D_;
  float* qb    = ws; ws += NR_*D_;
  float* kvb   = ws; ws += NR_*2*D_;
  float* attb  = ws; ws += NR_*D_;
  float* resb  = ws; ws += NR_*D_;
  float* partb = ws; ws += KSPLIT_*NR_*D_;
  ushort_t* us = (ushort_t*)ws;
  ushort_t* hnbf = us; us += NR_*KP_;
  ushort_t* ff1bf= us; us += NR_*FFN_;
  ushort_t* w1T  = us; us += NLAYERS_*FFN_*KP_;
  ushort_t* w2T  = us; us += NLAYERS_*D_*FFN_;
  // total ~ 26 MB

  k_build_x<<<(B_*L_*D_ + 255)/256, 256, 0, stream>>>(mel, x);
  k_w1t<<<(NLAYERS_*FFN_*KP_ + 255)/256, 256, 0, stream>>>(w1, w1T);
  k_w2t<<<(NLAYERS_*D_*FFN_ + 255)/256, 256, 0, stream>>>(w2, w2T);

  for (int l = 0; l < NLAYERS_; ++l) {
    k_ln  <<<NR_, 128, 0, stream>>>(x, ln_in_w + l*D_, ln_in_b + l*D_, xn);
    k_qkv <<<NR_, 256, 0, stream>>>(xn, wq + l*D_*D_, bq + l*D_,
                                    wkv + l*D_*2*D_, bkv + l*2*D_, qb, kvb);
    k_attn<<<dim3(NSEG_, B_), 320, 0, stream>>>(qb, kvb, attb);
    k_wo_res<<<NR_, 128, 0, stream>>>(attb, wo + l*D_*D_, bo + l*D_, x, resb);
    k_ln_bf<<<NR_, 128, 0, stream>>>(resb, ln_ff_w + l*D_, ln_ff_b + l*D_, hnbf);
    k_ffn1_mfma<<<dim3(NR_/64, FFN_/128), 256, 0, stream>>>(hnbf, w1T + l*FFN_*KP_, b1 + l*FFN_, ff1bf);
    k_ffn2_mfma<<<dim3(NR_/32, KSPLIT_), 64, 0, stream>>>(ff1bf, w2T + l*D_*FFN_, partb);
    k_ffn2_reduce_ln<<<NR_, 128, 0, stream>>>(partb, b2 + l*D_, resb,
                                              ln_o_w + l*D_, ln_o_b + l*D_, x);
  }

  k_proj<<<B_*TU_, 256, 0, stream>>>(x, pw, pb, out);
  k_len <<<1, 64, 0, stream>>>(lengths, out + B_*TU_*OUTD_);
}

// Round 3
// 255.768 us; speedup vs baseline: 3.7356x; 1.4479x over previous
//
#include <hip/hip_runtime.h>
#include <math.h>

#define B_    2
#define TU_   1024
#define D_    80
#define H_    8
#define DH_   10
#define FFN_  2048
#define SEG_  32
#define RC_   8
#define LC_   50
#define NSEG_ 32
#define RCT_  256
#define L_    1280
#define NLAYERS_ 4
#define OUTD_ 768
#define EPS_  1e-5f
#define SCALE_ 0.31622776601683794f   // 10^-0.5
#define NR_   (B_*L_)                 // 2560 rows
#define KP_   96                      // K=80 padded to 96 for MFMA
#define KSPLIT_ 8
#define KCH_  (FFN_/KSPLIT_)          // 256

typedef __attribute__((ext_vector_type(8))) short bf16x8;
typedef __attribute__((ext_vector_type(4))) float f32x4;
typedef unsigned short ushort_t;

__device__ inline ushort_t f2bf(float f) {
  union { float f; unsigned u; } x; x.f = f;
  unsigned r = x.u + 0x7fffu + ((x.u >> 16) & 1u);   // RNE
  return (ushort_t)(r >> 16);
}

// ---------------- gather x0 = [r ; u] ----------------
__global__ void k_build_x(const float* __restrict__ mel, float* __restrict__ x) {
  int idx = blockIdx.x * blockDim.x + threadIdx.x;
  if (idx >= B_*L_*D_) return;
  int d = idx % D_;
  int i = (idx / D_) % L_;
  int b = idx / (D_*L_);
  int srow;
  if (i < RCT_) { int seg = i / RC_, j = i % RC_; srow = (seg+1)*SEG_ + j; }
  else          { srow = i - RCT_; }
  x[idx] = mel[(b*(TU_+RC_) + srow)*D_ + d];
}

// ---------------- weight conversion (once) ----------------
__global__ void k_w1t(const float* __restrict__ w1, ushort_t* __restrict__ w1T) {
  int idx = blockIdx.x * blockDim.x + threadIdx.x;
  if (idx >= NLAYERS_*FFN_*KP_) return;
  int k = idx % KP_;
  int n = (idx / KP_) % FFN_;
  int l = idx / (KP_*FFN_);
  float v = (k < D_) ? w1[(l*D_ + k)*FFN_ + n] : 0.f;
  w1T[idx] = f2bf(v);
}
__global__ void k_w2t(const float* __restrict__ w2, ushort_t* __restrict__ w2T) {
  int idx = blockIdx.x * blockDim.x + threadIdx.x;
  if (idx >= NLAYERS_*D_*FFN_) return;
  int k = idx % FFN_;
  int n = (idx / FFN_) % D_;
  int l = idx / (FFN_*D_);
  w2T[idx] = f2bf(w2[(l*FFN_ + k)*D_ + n]);
}

// ---------------- fused LayerNorm + QKV projection ----------------
__global__ __launch_bounds__(256) void k_ln_qkv(const float* __restrict__ x,
    const float* __restrict__ lw, const float* __restrict__ lb,
    const float* __restrict__ wq, const float* __restrict__ bq,
    const float* __restrict__ wkv, const float* __restrict__ bkv,
    float* __restrict__ q, float* __restrict__ kv) {
  int row = blockIdx.x, tid = threadIdx.x;
  __shared__ float s1[128], s2[128];
  __shared__ float xr[D_];
  float v = 0.f;
  if (tid < 128) {
    v = (tid < D_) ? x[row*D_ + tid] : 0.f;
    s1[tid] = v; s2[tid] = v*v;
  }
  __syncthreads();
  for (int off = 64; off > 0; off >>= 1) {
    if (tid < off) { s1[tid] += s1[tid+off]; s2[tid] += s2[tid+off]; }
    __syncthreads();
  }
  float mean = s1[0] * (1.f/D_);
  float var  = s2[0] * (1.f/D_) - mean*mean;
  float inv  = rsqrtf(var + EPS_);
  if (tid < D_) xr[tid] = (v - mean) * inv * lw[tid] + lb[tid];
  __syncthreads();
  if (tid < D_) {
    float acc = 0.f;
    #pragma unroll 8
    for (int k = 0; k < D_; ++k) acc += xr[k] * wq[k*D_ + tid];
    q[row*D_ + tid] = (acc + bq[tid]) * SCALE_;
  } else if (tid < D_ + 2*D_) {
    int c = tid - D_;
    float acc = 0.f;
    #pragma unroll 8
    for (int k = 0; k < D_; ++k) acc += xr[k] * wkv[k*2*D_ + c];
    kv[row*2*D_ + c] = acc + bkv[c];
  }
}

// ---------------- block-sparse attention v2: one block per (seg, batch, head) ----------------
__global__ __launch_bounds__(256) void k_attn(const float* __restrict__ q,
    const float* __restrict__ kv, float* __restrict__ att) {
  int seg = blockIdx.x, b = blockIdx.y, h = blockIdx.z;
  int tid = threadIdx.x;
  int seg_start = seg*SEG_ - LC_; if (seg_start < 0) seg_start = 0;
  int kc = RC_ + (seg+1)*SEG_ - seg_start;       // <= 90
  __shared__ float Ksh[90][DH_];
  __shared__ float Vsh[90][DH_];
  __shared__ float Qsh[40][DH_];
  __shared__ float Ssh[40][90];
  __shared__ float inv_sh[40];
  for (int idx = tid; idx < kc*DH_; idx += 256) {
    int kk = idx / DH_, d = idx % DH_;
    int krow = (kk < RC_) ? seg*RC_ + kk : RCT_ + seg_start + (kk - RC_);
    const float* base = kv + (b*L_ + krow)*2*D_ + h*DH_ + d;
    Ksh[kk][d] = base[0];
    Vsh[kk][d] = base[D_];
  }
  for (int idx = tid; idx < 40*DH_; idx += 256) {
    int qi = idx / DH_, d = idx % DH_;
    int qrow = (qi < RC_) ? seg*RC_ + qi : RCT_ + seg*SEG_ + (qi - RC_);
    Qsh[qi][d] = q[(b*L_ + qrow)*D_ + h*DH_ + d];
  }
  __syncthreads();
  // phase 1: raw scores
  for (int p = tid; p < 40*kc; p += 256) {
    int qi = p / kc, kk = p - qi*kc;
    float s = 0.f;
    #pragma unroll
    for (int d = 0; d < DH_; ++d) s += Qsh[qi][d] * Ksh[kk][d];
    Ssh[qi][kk] = s;
  }
  __syncthreads();
  // phase 2: per-row softmax (40 rows x 4 lanes)
  if (tid < 160) {
    int row = tid >> 2, j = tid & 3;
    float pm = -INFINITY;
    for (int kk = j; kk < kc; kk += 4) pm = fmaxf(pm, Ssh[row][kk]);
    pm = fmaxf(pm, __shfl_xor(pm, 1, 4));
    pm = fmaxf(pm, __shfl_xor(pm, 2, 4));
    float ps = 0.f;
    for (int kk = j; kk < kc; kk += 4) {
      float e = expf(Ssh[row][kk] - pm);
      Ssh[row][kk] = e;
      ps += e;
    }
    ps += __shfl_xor(ps, 1, 4);
    ps += __shfl_xor(ps, 2, 4);
    if (j == 0) inv_sh[row] = 1.f / ps;
  }
  __syncthreads();
  // phase 3: P @ V
  for (int o = tid; o < 40*DH_; o += 256) {
    int qi = o / DH_, d = o - qi*DH_;
    float acc = 0.f;
    for (int kk = 0; kk < kc; ++kk) acc += Ssh[qi][kk] * Vsh[kk][d];
    int qrow = (qi < RC_) ? seg*RC_ + qi : RCT_ + seg*SEG_ + (qi - RC_);
    att[(b*L_ + qrow)*D_ + h*DH_ + d] = acc * inv_sh[qi];
  }
}

// ---------------- fused out-proj + residual + LayerNorm_ff -> bf16 ----------------
__global__ __launch_bounds__(128) void k_wo_res_lnbf(const float* __restrict__ att,
    const float* __restrict__ wo, const float* __restrict__ bo,
    const float* __restrict__ x, float* __restrict__ res,
    const float* __restrict__ lw, const float* __restrict__ lb,
    ushort_t* __restrict__ hnbf) {
  int row = blockIdx.x, tid = threadIdx.x;
  __shared__ float ar[D_];
  __shared__ float s1[128], s2[128];
  if (tid < D_) ar[tid] = att[row*D_ + tid];
  __syncthreads();
  float v = 0.f;
  if (tid < D_) {
    float acc = 0.f;
    #pragma unroll 8
    for (int k = 0; k < D_; ++k) acc += ar[k] * wo[k*D_ + tid];
    v = acc + bo[tid] + x[row*D_ + tid];
    res[row*D_ + tid] = v;
  }
  s1[tid] = v; s2[tid] = v*v;
  __syncthreads();
  for (int off = 64; off > 0; off >>= 1) {
    if (tid < off) { s1[tid] += s1[tid+off]; s2[tid] += s2[tid+off]; }
    __syncthreads();
  }
  float mean = s1[0] * (1.f/D_);
  float var  = s2[0] * (1.f/D_) - mean*mean;
  float inv  = rsqrtf(var + EPS_);
  if (tid < D_)       hnbf[row*KP_ + tid] = f2bf((v - mean) * inv * lw[tid] + lb[tid]);
  else if (tid < KP_) hnbf[row*KP_ + tid] = 0;
}

// ---------------- FFN1 MFMA ----------------
__global__ __launch_bounds__(256) void k_ffn1_mfma(const ushort_t* __restrict__ hnb,
    const ushort_t* __restrict__ w1T, const float* __restrict__ b1, ushort_t* __restrict__ ff1) {
  int wv = threadIdx.x >> 6, lane = threadIdx.x & 63;
  int bm = blockIdx.x * 64;
  int bn = blockIdx.y * 128 + wv*32;
  int r = lane & 15, g = lane >> 4;
  f32x4 acc[4][2] = {};
  const ushort_t* Ab = hnb + (bm + r)*KP_ + g*8;
  const ushort_t* Bb = w1T + (bn + r)*KP_ + g*8;
  #pragma unroll
  for (int ks = 0; ks < KP_; ks += 32) {
    bf16x8 a[4], bfr[2];
    #pragma unroll
    for (int mf = 0; mf < 4; ++mf) a[mf]   = *(const bf16x8*)(Ab + mf*16*KP_ + ks);
    #pragma unroll
    for (int nf = 0; nf < 2; ++nf) bfr[nf] = *(const bf16x8*)(Bb + nf*16*KP_ + ks);
    #pragma unroll
    for (int mf = 0; mf < 4; ++mf)
      #pragma unroll
      for (int nf = 0; nf < 2; ++nf)
        acc[mf][nf] = __builtin_amdgcn_mfma_f32_16x16x32_bf16(a[mf], bfr[nf], acc[mf][nf], 0, 0, 0);
  }
  #pragma unroll
  for (int mf = 0; mf < 4; ++mf)
    #pragma unroll
    for (int nf = 0; nf < 2; ++nf) {
      int col = bn + nf*16 + r;
      float bc = b1[col];
      #pragma unroll
      for (int rr = 0; rr < 4; ++rr) {
        int row = bm + mf*16 + g*4 + rr;
        float v = acc[mf][nf][rr] + bc;
        ff1[row*FFN_ + col] = f2bf(fmaxf(v, 0.f));
      }
    }
}

// ---------------- FFN2 MFMA: fp32 partials (K split 8) ----------------
__global__ __launch_bounds__(64) void k_ffn2_mfma(const ushort_t* __restrict__ ff1,
    const ushort_t* __restrict__ w2T, float* __restrict__ part) {
  int bm = blockIdx.x * 32;
  int kc = blockIdx.y;
  int lane = threadIdx.x;
  int r = lane & 15, g = lane >> 4;
  f32x4 acc[2][5] = {};
  const ushort_t* Ab = ff1 + (bm + r)*FFN_ + kc*KCH_ + g*8;
  const ushort_t* Bb = w2T + r*FFN_ + kc*KCH_ + g*8;
  #pragma unroll
  for (int ks = 0; ks < KCH_; ks += 32) {
    bf16x8 a[2], bfr[5];
    #pragma unroll
    for (int nf = 0; nf < 5; ++nf) bfr[nf] = *(const bf16x8*)(Bb + nf*16*FFN_ + ks);
    #pragma unroll
    for (int mf = 0; mf < 2; ++mf) a[mf]   = *(const bf16x8*)(Ab + mf*16*FFN_ + ks);
    #pragma unroll
    for (int mf = 0; mf < 2; ++mf)
      #pragma unroll
      for (int nf = 0; nf < 5; ++nf)
        acc[mf][nf] = __builtin_amdgcn_mfma_f32_16x16x32_bf16(a[mf], bfr[nf], acc[mf][nf], 0, 0, 0);
  }
  float* pbase = part + (size_t)kc*NR_*D_ + (size_t)bm*D_;
  #pragma unroll
  for (int mf = 0; mf < 2; ++mf)
    #pragma unroll
    for (int nf = 0; nf < 5; ++nf)
      #pragma unroll
      for (int rr = 0; rr < 4; ++rr) {
        int row = mf*16 + g*4 + rr;
        int col = nf*16 + r;
        pbase[row*D_ + col] = acc[mf][nf][rr];
      }
}

// ---------------- FFN2 reduce + bias + residual + LayerNorm_out -> x ----------------
__global__ __launch_bounds__(128) void k_ffn2_reduce_ln(const float* __restrict__ part,
    const float* __restrict__ b2, const float* __restrict__ res,
    const float* __restrict__ w, const float* __restrict__ b, float* __restrict__ xout) {
  int row = blockIdx.x, tid = threadIdx.x;
  __shared__ float s1[128], s2[128];
  float v = 0.f;
  if (tid < D_) {
    v = b2[tid] + res[row*D_ + tid];
    #pragma unroll
    for (int c = 0; c < KSPLIT_; ++c) v += part[((size_t)c*NR_ + row)*D_ + tid];
  }
  s1[tid] = v; s2[tid] = v*v;
  __syncthreads();
  for (int off = 64; off > 0; off >>= 1) {
    if (tid < off) { s1[tid] += s1[tid+off]; s2[tid] += s2[tid+off]; }
    __syncthreads();
  }
  float mean = s1[0] * (1.f/D_);
  float var  = s2[0] * (1.f/D_) - mean*mean;
  float inv  = rsqrtf(var + EPS_);
  if (tid < D_) xout[row*D_ + tid] = (v - mean) * inv * w[tid] + b[tid];
}

// ---------------- final projection u@(80x768)+pb ----------------
__global__ __launch_bounds__(256) void k_proj(const float* __restrict__ x,
    const float* __restrict__ pw, const float* __restrict__ pb, float* __restrict__ out) {
  int row = blockIdx.x;            // 0..2047 = b*1024+t
  int tid = threadIdx.x;
  int b = row >> 10, t = row & 1023;
  int xrow = b*L_ + RCT_ + t;
  __shared__ float xr[D_];
  if (tid < D_) xr[tid] = x[xrow*D_ + tid];
  __syncthreads();
  for (int c = tid; c < OUTD_; c += 256) {
    float acc = 0.f;
    #pragma unroll 8
    for (int k = 0; k < D_; ++k) acc += xr[k] * pw[k*OUTD_ + c];
    out[row*OUTD_ + c] = acc + pb[c];
  }
}

__global__ void k_len(const int* __restrict__ len, float* __restrict__ out) {
  int t = threadIdx.x;
  if (t < B_) out[t] = (float)len[t];
}

extern "C" void kernel_launch(void* const* d_in, const int* in_sizes, int n_in,
                              void* d_out, int out_size, void* d_ws, size_t ws_size,
                              hipStream_t stream) {
  const float* mel     = (const float*)d_in[0];
  const int*   lengths = (const int*)  d_in[1];
  const float* ln_in_w = (const float*)d_in[2];
  const float* ln_in_b = (const float*)d_in[3];
  const float* wq      = (const float*)d_in[4];
  const float* bq      = (const float*)d_in[5];
  const float* wkv     = (const float*)d_in[6];
  const float* bkv     = (const float*)d_in[7];
  const float* wo      = (const float*)d_in[8];
  const float* bo      = (const float*)d_in[9];
  const float* ln_ff_w = (const float*)d_in[10];
  const float* ln_ff_b = (const float*)d_in[11];
  const float* w1      = (const float*)d_in[12];
  const float* b1      = (const float*)d_in[13];
  const float* w2      = (const float*)d_in[14];
  const float* b2      = (const float*)d_in[15];
  const float* ln_o_w  = (const float*)d_in[16];
  const float* ln_o_b  = (const float*)d_in[17];
  const float* pw      = (const float*)d_in[18];
  const float* pb      = (const float*)d_in[19];
  float* out = (float*)d_out;

  float* ws = (float*)d_ws;
  float* x     = ws; ws += NR_*D_;
  float* qb    = ws; ws += NR_*D_;
  float* kvb   = ws; ws += NR_*2*D_;
  float* attb  = ws; ws += NR_*D_;
  float* resb  = ws; ws += NR_*D_;
  float* partb = ws; ws += KSPLIT_*NR_*D_;
  ushort_t* us = (ushort_t*)ws;
  ushort_t* hnbf = us; us += NR_*KP_;
  ushort_t* ff1bf= us; us += NR_*FFN_;
  ushort_t* w1T  = us; us += NLAYERS_*FFN_*KP_;
  ushort_t* w2T  = us; us += NLAYERS_*D_*FFN_;

  k_build_x<<<(B_*L_*D_ + 255)/256, 256, 0, stream>>>(mel, x);
  k_w1t<<<(NLAYERS_*FFN_*KP_ + 255)/256, 256, 0, stream>>>(w1, w1T);
  k_w2t<<<(NLAYERS_*D_*FFN_ + 255)/256, 256, 0, stream>>>(w2, w2T);

  for (int l = 0; l < NLAYERS_; ++l) {
    k_ln_qkv<<<NR_, 256, 0, stream>>>(x, ln_in_w + l*D_, ln_in_b + l*D_,
                                      wq + l*D_*D_, bq + l*D_,
                                      wkv + l*D_*2*D_, bkv + l*2*D_, qb, kvb);
    k_attn<<<dim3(NSEG_, B_, H_), 256, 0, stream>>>(qb, kvb, attb);
    k_wo_res_lnbf<<<NR_, 128, 0, stream>>>(attb, wo + l*D_*D_, bo + l*D_, x, resb,
                                           ln_ff_w + l*D_, ln_ff_b + l*D_, hnbf);
    k_ffn1_mfma<<<dim3(NR_/64, FFN_/128), 256, 0, stream>>>(hnbf, w1T + l*FFN_*KP_, b1 + l*FFN_, ff1bf);
    k_ffn2_mfma<<<dim3(NR_/32, KSPLIT_), 64, 0, stream>>>(ff1bf, w2T + l*D_*FFN_, partb);
    k_ffn2_reduce_ln<<<NR_, 128, 0, stream>>>(partb, b2 + l*D_, resb,
                                              ln_o_w + l*D_, ln_o_b + l*D_, x);
  }

  k_proj<<<B_*TU_, 256, 0, stream>>>(x, pw, pb, out);
  k_len <<<1, 64, 0, stream>>>(lengths, out + B_*TU_*OUTD_);
}

// Round 4
// 204.740 us; speedup vs baseline: 4.6667x; 1.2492x over previous
//
#include <hip/hip_runtime.h>
#include <math.h>

#define B_    2
#define TU_   1024
#define D_    80
#define H_    8
#define DH_   10
#define FFN_  2048
#define SEG_  32
#define RC_   8
#define LC_   50
#define NSEG_ 32
#define RCT_  256
#define L_    1280
#define NLAYERS_ 4
#define OUTD_ 768
#define EPS_  1e-5f
#define SCALE_ 0.31622776601683794f
#define NR_   (B_*L_)                 // 2560
#define KP_   96                      // K pad 80->96

typedef __attribute__((ext_vector_type(8))) short bf16x8;
typedef __attribute__((ext_vector_type(4))) float f32x4;
typedef unsigned short ushort_t;

__device__ inline ushort_t f2bf(float f) {
  union { float f; unsigned u; } x; x.f = f;
  unsigned r = x.u + 0x7fffu + ((x.u >> 16) & 1u);   // RNE
  return (ushort_t)(r >> 16);
}

// ============ one-shot weight prep: transpose+bf16 (+scale/pad folds) ============
#define S1_ (NLAYERS_*FFN_*KP_)        // w1T [l][n2048][k96]
#define S2_ (NLAYERS_*D_*FFN_)         // w2T [l][n80][k2048]
#define S3_ (NLAYERS_*256*KP_)         // wqkvT [l][n256][k96] (scale folded in q cols)
#define S4_ (NLAYERS_*D_*KP_)          // woT [l][n80][k96]
#define S5_ (OUTD_*KP_)                // pwT [n768][k96]
#define S6_ (NLAYERS_*240)             // bqkv fp32 [l][240]
#define WPREP_N_ (S1_+S2_+S3_+S4_+S5_+S6_)

__global__ void k_wprep(const float* __restrict__ w1, const float* __restrict__ w2,
    const float* __restrict__ wq, const float* __restrict__ wkv,
    const float* __restrict__ wo, const float* __restrict__ pw,
    const float* __restrict__ bq, const float* __restrict__ bkv,
    ushort_t* __restrict__ w1T, ushort_t* __restrict__ w2T,
    ushort_t* __restrict__ wqkvT, ushort_t* __restrict__ woT,
    ushort_t* __restrict__ pwT, float* __restrict__ bqkv) {
  int idx = blockIdx.x * blockDim.x + threadIdx.x;
  if (idx < S1_) {
    int k = idx % KP_, n = (idx / KP_) % FFN_, l = idx / (KP_*FFN_);
    w1T[idx] = (k < D_) ? f2bf(w1[(l*D_ + k)*FFN_ + n]) : 0;
    return;
  }
  idx -= S1_;
  if (idx < S2_) {
    int k = idx % FFN_, n = (idx / FFN_) % D_, l = idx / (FFN_*D_);
    w2T[idx] = f2bf(w2[(l*FFN_ + k)*D_ + n]);
    return;
  }
  idx -= S2_;
  if (idx < S3_) {
    int k = idx % KP_, n = (idx / KP_) % 256, l = idx / (KP_*256);
    float v = 0.f;
    if (k < D_ && n < 240) {
      if (n < D_) v = wq[(l*D_ + k)*D_ + n] * SCALE_;
      else        v = wkv[(l*D_ + k)*2*D_ + (n - D_)];
    }
    wqkvT[idx] = f2bf(v);
    return;
  }
  idx -= S3_;
  if (idx < S4_) {
    int k = idx % KP_, n = (idx / KP_) % D_, l = idx / (KP_*D_);
    woT[idx] = (k < D_) ? f2bf(wo[(l*D_ + k)*D_ + n]) : 0;
    return;
  }
  idx -= S4_;
  if (idx < S5_) {
    int k = idx % KP_, n = idx / KP_;
    pwT[idx] = (k < D_) ? f2bf(pw[k*OUTD_ + n]) : 0;
    return;
  }
  idx -= S5_;
  if (idx < S6_) {
    int c = idx % 240, l = idx / 240;
    bqkv[idx] = (c < D_) ? bq[l*D_ + c] * SCALE_ : bkv[l*2*D_ + (c - D_)];
  }
}

// ============ build x (gather) + layer-0 LN_in -> xnbf ============
__global__ __launch_bounds__(128) void k_build_ln(const float* __restrict__ mel,
    const float* __restrict__ lw, const float* __restrict__ lb,
    float* __restrict__ x, ushort_t* __restrict__ xnbf) {
  int row = blockIdx.x, tid = threadIdx.x;
  int b = row / L_, i = row % L_;
  int srow;
  if (i < RCT_) { int seg = i / RC_, j = i % RC_; srow = (seg+1)*SEG_ + j; }
  else          { srow = i - RCT_; }
  __shared__ float s1[128], s2[128];
  float v = (tid < D_) ? mel[(b*(TU_+RC_) + srow)*D_ + tid] : 0.f;
  if (tid < D_) x[row*D_ + tid] = v;
  s1[tid] = v; s2[tid] = v*v;
  __syncthreads();
  for (int off = 64; off > 0; off >>= 1) {
    if (tid < off) { s1[tid] += s1[tid+off]; s2[tid] += s2[tid+off]; }
    __syncthreads();
  }
  float mean = s1[0] * (1.f/D_);
  float var  = s2[0] * (1.f/D_) - mean*mean;
  float inv  = rsqrtf(var + EPS_);
  if (tid < D_)       xnbf[row*KP_ + tid] = f2bf((v - mean) * inv * lw[tid] + lb[tid]);
  else if (tid < KP_) xnbf[row*KP_ + tid] = 0;
}

// ============ QKV MFMA: [2560x96] @ [96x256pad] -> q(scaled)/kv fp32 ============
// grid (40, 2), 256 thr. wave: 64 rows x 32 cols.
__global__ __launch_bounds__(256) void k_qkv_mfma(const ushort_t* __restrict__ xnbf,
    const ushort_t* __restrict__ wqkvT, const float* __restrict__ bqkv,
    float* __restrict__ q, float* __restrict__ kv) {
  int wv = threadIdx.x >> 6, lane = threadIdx.x & 63;
  int bm = blockIdx.x * 64;
  int bn = blockIdx.y * 128 + wv*32;
  int r = lane & 15, g = lane >> 4;
  f32x4 acc[4][2] = {};
  const ushort_t* Ab = xnbf + (bm + r)*KP_ + g*8;
  const ushort_t* Bb = wqkvT + (bn + r)*KP_ + g*8;
  #pragma unroll
  for (int ks = 0; ks < KP_; ks += 32) {
    bf16x8 a[4], bfr[2];
    #pragma unroll
    for (int mf = 0; mf < 4; ++mf) a[mf]   = *(const bf16x8*)(Ab + mf*16*KP_ + ks);
    #pragma unroll
    for (int nf = 0; nf < 2; ++nf) bfr[nf] = *(const bf16x8*)(Bb + nf*16*KP_ + ks);
    #pragma unroll
    for (int mf = 0; mf < 4; ++mf)
      #pragma unroll
      for (int nf = 0; nf < 2; ++nf)
        acc[mf][nf] = __builtin_amdgcn_mfma_f32_16x16x32_bf16(a[mf], bfr[nf], acc[mf][nf], 0, 0, 0);
  }
  #pragma unroll
  for (int mf = 0; mf < 4; ++mf)
    #pragma unroll
    for (int nf = 0; nf < 2; ++nf) {
      int col = bn + nf*16 + r;
      if (col >= 240) continue;
      float bc = bqkv[col];
      #pragma unroll
      for (int rr = 0; rr < 4; ++rr) {
        int row = bm + mf*16 + g*4 + rr;
        float v = acc[mf][nf][rr] + bc;
        if (col < D_) q[row*D_ + col] = v;
        else          kv[row*2*D_ + (col - D_)] = v;
      }
    }
}

// ============ block-sparse attention -> attb bf16 [2560][96] ============
__global__ __launch_bounds__(256) void k_attn(const float* __restrict__ q,
    const float* __restrict__ kv, ushort_t* __restrict__ att) {
  int seg = blockIdx.x, b = blockIdx.y, h = blockIdx.z;
  int tid = threadIdx.x;
  int seg_start = seg*SEG_ - LC_; if (seg_start < 0) seg_start = 0;
  int kc = RC_ + (seg+1)*SEG_ - seg_start;       // <= 90
  __shared__ float Ksh[90][DH_];
  __shared__ float Vsh[90][DH_];
  __shared__ float Qsh[40][DH_];
  __shared__ float Ssh[40][90];
  __shared__ float inv_sh[40];
  for (int idx = tid; idx < kc*DH_; idx += 256) {
    int kk = idx / DH_, d = idx % DH_;
    int krow = (kk < RC_) ? seg*RC_ + kk : RCT_ + seg_start + (kk - RC_);
    const float* base = kv + (b*L_ + krow)*2*D_ + h*DH_ + d;
    Ksh[kk][d] = base[0];
    Vsh[kk][d] = base[D_];
  }
  for (int idx = tid; idx < 40*DH_; idx += 256) {
    int qi = idx / DH_, d = idx % DH_;
    int qrow = (qi < RC_) ? seg*RC_ + qi : RCT_ + seg*SEG_ + (qi - RC_);
    Qsh[qi][d] = q[(b*L_ + qrow)*D_ + h*DH_ + d];
  }
  __syncthreads();
  for (int p = tid; p < 40*kc; p += 256) {
    int qi = p / kc, kk = p - qi*kc;
    float s = 0.f;
    #pragma unroll
    for (int d = 0; d < DH_; ++d) s += Qsh[qi][d] * Ksh[kk][d];
    Ssh[qi][kk] = s;
  }
  __syncthreads();
  if (tid < 160) {
    int row = tid >> 2, j = tid & 3;
    float pm = -INFINITY;
    for (int kk = j; kk < kc; kk += 4) pm = fmaxf(pm, Ssh[row][kk]);
    pm = fmaxf(pm, __shfl_xor(pm, 1, 4));
    pm = fmaxf(pm, __shfl_xor(pm, 2, 4));
    float ps = 0.f;
    for (int kk = j; kk < kc; kk += 4) {
      float e = expf(Ssh[row][kk] - pm);
      Ssh[row][kk] = e;
      ps += e;
    }
    ps += __shfl_xor(ps, 1, 4);
    ps += __shfl_xor(ps, 2, 4);
    if (j == 0) inv_sh[row] = 1.f / ps;
  }
  __syncthreads();
  for (int o = tid; o < 40*DH_; o += 256) {
    int qi = o / DH_, d = o - qi*DH_;
    float acc = 0.f;
    for (int kk = 0; kk < kc; ++kk) acc += Ssh[qi][kk] * Vsh[kk][d];
    int qrow = (qi < RC_) ? seg*RC_ + qi : RCT_ + seg*SEG_ + (qi - RC_);
    att[(b*L_ + qrow)*KP_ + h*DH_ + d] = f2bf(acc * inv_sh[qi]);
  }
  if (h == 0) {  // zero the K-pad cols 80..95 (each (seg,b) owns disjoint rows)
    for (int idx = tid; idx < 40*16; idx += 256) {
      int qi = idx >> 4, c = D_ + (idx & 15);
      int qrow = (qi < RC_) ? seg*RC_ + qi : RCT_ + seg*SEG_ + (qi - RC_);
      att[(b*L_ + qrow)*KP_ + c] = 0;
    }
  }
}

// ============ WO MFMA + bias + residual + LN_ff -> res fp32, hnbf bf16 ============
// grid 160, 1 wave. wave: 16 rows x 80 cols (5 N-frags), K=96.
__global__ __launch_bounds__(64) void k_wo_res_ln(const ushort_t* __restrict__ attb,
    const ushort_t* __restrict__ woT, const float* __restrict__ bo,
    const float* __restrict__ x, float* __restrict__ res,
    const float* __restrict__ lw, const float* __restrict__ lb,
    ushort_t* __restrict__ hnbf) {
  int lane = threadIdx.x;
  int bm = blockIdx.x * 16;
  int r = lane & 15, g = lane >> 4;
  f32x4 acc[5] = {};
  const ushort_t* Ab = attb + (bm + r)*KP_ + g*8;
  const ushort_t* Bb = woT + r*KP_ + g*8;
  #pragma unroll
  for (int ks = 0; ks < KP_; ks += 32) {
    bf16x8 a = *(const bf16x8*)(Ab + ks);
    #pragma unroll
    for (int nf = 0; nf < 5; ++nf) {
      bf16x8 bf = *(const bf16x8*)(Bb + nf*16*KP_ + ks);
      acc[nf] = __builtin_amdgcn_mfma_f32_16x16x32_bf16(a, bf, acc[nf], 0, 0, 0);
    }
  }
  // epilogue: vals -> res, then per-row LN over 80 cols
  float lwv[5], lbv[5], bov[5];
  #pragma unroll
  for (int nf = 0; nf < 5; ++nf) {
    int col = nf*16 + r;
    lwv[nf] = lw[col]; lbv[nf] = lb[col]; bov[nf] = bo[col];
  }
  #pragma unroll
  for (int rr = 0; rr < 4; ++rr) {
    int row = bm + g*4 + rr;
    float v[5];
    float s = 0.f, ss = 0.f;
    #pragma unroll
    for (int nf = 0; nf < 5; ++nf) {
      int col = nf*16 + r;
      v[nf] = acc[nf][rr] + bov[nf] + x[row*D_ + col];
      res[row*D_ + col] = v[nf];
      s += v[nf]; ss += v[nf]*v[nf];
    }
    s  += __shfl_xor(s, 1, 16);  ss += __shfl_xor(ss, 1, 16);
    s  += __shfl_xor(s, 2, 16);  ss += __shfl_xor(ss, 2, 16);
    s  += __shfl_xor(s, 4, 16);  ss += __shfl_xor(ss, 4, 16);
    s  += __shfl_xor(s, 8, 16);  ss += __shfl_xor(ss, 8, 16);
    float mean = s * (1.f/D_);
    float var  = ss * (1.f/D_) - mean*mean;
    float inv  = rsqrtf(var + EPS_);
    #pragma unroll
    for (int nf = 0; nf < 5; ++nf) {
      int col = nf*16 + r;
      hnbf[row*KP_ + col] = f2bf((v[nf] - mean) * inv * lwv[nf] + lbv[nf]);
    }
    hnbf[row*KP_ + D_ + r] = 0;   // pad cols 80..95
  }
}

// ============ FFN1 MFMA: bias+relu -> ff1 bf16 ============
__global__ __launch_bounds__(256) void k_ffn1_mfma(const ushort_t* __restrict__ hnb,
    const ushort_t* __restrict__ w1T, const float* __restrict__ b1, ushort_t* __restrict__ ff1) {
  int wv = threadIdx.x >> 6, lane = threadIdx.x & 63;
  int bm = blockIdx.x * 64;
  int bn = blockIdx.y * 128 + wv*32;
  int r = lane & 15, g = lane >> 4;
  f32x4 acc[4][2] = {};
  const ushort_t* Ab = hnb + (bm + r)*KP_ + g*8;
  const ushort_t* Bb = w1T + (bn + r)*KP_ + g*8;
  #pragma unroll
  for (int ks = 0; ks < KP_; ks += 32) {
    bf16x8 a[4], bfr[2];
    #pragma unroll
    for (int mf = 0; mf < 4; ++mf) a[mf]   = *(const bf16x8*)(Ab + mf*16*KP_ + ks);
    #pragma unroll
    for (int nf = 0; nf < 2; ++nf) bfr[nf] = *(const bf16x8*)(Bb + nf*16*KP_ + ks);
    #pragma unroll
    for (int mf = 0; mf < 4; ++mf)
      #pragma unroll
      for (int nf = 0; nf < 2; ++nf)
        acc[mf][nf] = __builtin_amdgcn_mfma_f32_16x16x32_bf16(a[mf], bfr[nf], acc[mf][nf], 0, 0, 0);
  }
  #pragma unroll
  for (int mf = 0; mf < 4; ++mf)
    #pragma unroll
    for (int nf = 0; nf < 2; ++nf) {
      int col = bn + nf*16 + r;
      float bc = b1[col];
      #pragma unroll
      for (int rr = 0; rr < 4; ++rr) {
        int row = bm + mf*16 + g*4 + rr;
        ff1[row*FFN_ + col] = f2bf(fmaxf(acc[mf][nf][rr] + bc, 0.f));
      }
    }
}

// ============ FFN2 fused: MFMA (8 waves split K) + LDS reduce + bias + residual
//              + LN_out -> x fp32, then LN_in(next)/plain -> xnbf bf16 ============
// grid 160, 512 thr. 16 rows per block.
__global__ __launch_bounds__(512) void k_ffn2_fused(const ushort_t* __restrict__ ff1,
    const ushort_t* __restrict__ w2T, const float* __restrict__ b2,
    const float* __restrict__ res,
    const float* __restrict__ low, const float* __restrict__ lob,
    const float* __restrict__ liw, const float* __restrict__ lib, int mode,
    float* __restrict__ x, ushort_t* __restrict__ xnbf) {
  int tid = threadIdx.x;
  int wv = tid >> 6, lane = tid & 63;
  int r = lane & 15, g = lane >> 4;
  int bm = blockIdx.x * 16;
  __shared__ float red[8][16][D_];
  f32x4 acc[5] = {};
  const ushort_t* Ab = ff1 + (bm + r)*FFN_ + wv*256 + g*8;
  const ushort_t* Bb = w2T + r*FFN_ + wv*256 + g*8;
  #pragma unroll
  for (int ks = 0; ks < 256; ks += 32) {
    bf16x8 a = *(const bf16x8*)(Ab + ks);
    #pragma unroll
    for (int nf = 0; nf < 5; ++nf) {
      bf16x8 bf = *(const bf16x8*)(Bb + nf*16*FFN_ + ks);
      acc[nf] = __builtin_amdgcn_mfma_f32_16x16x32_bf16(a, bf, acc[nf], 0, 0, 0);
    }
  }
  #pragma unroll
  for (int nf = 0; nf < 5; ++nf)
    #pragma unroll
    for (int rr = 0; rr < 4; ++rr)
      red[wv][g*4 + rr][nf*16 + r] = acc[nf][rr];
  __syncthreads();
  // sum 8 partials + bias + residual
  for (int e = tid; e < 16*D_; e += 512) {
    int row = e / D_, col = e % D_;
    float s = red[0][row][col];
    #pragma unroll
    for (int w = 1; w < 8; ++w) s += red[w][row][col];
    red[0][row][col] = s + b2[col] + res[(bm+row)*D_ + col];
  }
  __syncthreads();
  if (tid < 256) {
    int row = tid >> 4, j = tid & 15;
    float v[5], s = 0.f, ss = 0.f;
    #pragma unroll
    for (int c = 0; c < 5; ++c) {
      v[c] = red[0][row][j + c*16];
      s += v[c]; ss += v[c]*v[c];
    }
    s  += __shfl_xor(s, 1, 16);  ss += __shfl_xor(ss, 1, 16);
    s  += __shfl_xor(s, 2, 16);  ss += __shfl_xor(ss, 2, 16);
    s  += __shfl_xor(s, 4, 16);  ss += __shfl_xor(ss, 4, 16);
    s  += __shfl_xor(s, 8, 16);  ss += __shfl_xor(ss, 8, 16);
    float mean = s * (1.f/D_);
    float var  = ss * (1.f/D_) - mean*mean;
    float inv  = rsqrtf(var + EPS_);
    int grow = bm + row;
    float xs[5];
    float s2 = 0.f, ss2 = 0.f;
    #pragma unroll
    for (int c = 0; c < 5; ++c) {
      int col = j + c*16;
      xs[c] = (v[c] - mean) * inv * low[col] + lob[col];
      x[grow*D_ + col] = xs[c];
      s2 += xs[c]; ss2 += xs[c]*xs[c];
    }
    if (mode == 0) {  // second LN with next-layer ln_in
      s2  += __shfl_xor(s2, 1, 16);  ss2 += __shfl_xor(ss2, 1, 16);
      s2  += __shfl_xor(s2, 2, 16);  ss2 += __shfl_xor(ss2, 2, 16);
      s2  += __shfl_xor(s2, 4, 16);  ss2 += __shfl_xor(ss2, 4, 16);
      s2  += __shfl_xor(s2, 8, 16);  ss2 += __shfl_xor(ss2, 8, 16);
      float m2 = s2 * (1.f/D_);
      float v2 = ss2 * (1.f/D_) - m2*m2;
      float i2 = rsqrtf(v2 + EPS_);
      #pragma unroll
      for (int c = 0; c < 5; ++c) {
        int col = j + c*16;
        xnbf[grow*KP_ + col] = f2bf((xs[c] - m2) * i2 * liw[col] + lib[col]);
      }
    } else {          // plain bf16 copy for final projection
      #pragma unroll
      for (int c = 0; c < 5; ++c)
        xnbf[grow*KP_ + j + c*16] = f2bf(xs[c]);
    }
    xnbf[grow*KP_ + D_ + j] = 0;
  }
}

// ============ final proj MFMA: u[2048x96] @ pwT -> out [2048x768] ============
// grid (16, 6, 2), 256 thr.
__global__ __launch_bounds__(256) void k_proj_mfma(const ushort_t* __restrict__ xbf,
    const ushort_t* __restrict__ pwT, const float* __restrict__ pb,
    float* __restrict__ out) {
  int wv = threadIdx.x >> 6, lane = threadIdx.x & 63;
  int bm = blockIdx.x * 64;
  int bn = blockIdx.y * 128 + wv*32;
  int b  = blockIdx.z;
  int r = lane & 15, g = lane >> 4;
  f32x4 acc[4][2] = {};
  const ushort_t* Ab = xbf + ((size_t)(b*L_ + RCT_ + bm) + r)*KP_ + g*8;
  const ushort_t* Bb = pwT + (bn + r)*KP_ + g*8;
  #pragma unroll
  for (int ks = 0; ks < KP_; ks += 32) {
    bf16x8 a[4], bfr[2];
    #pragma unroll
    for (int mf = 0; mf < 4; ++mf) a[mf]   = *(const bf16x8*)(Ab + mf*16*KP_ + ks);
    #pragma unroll
    for (int nf = 0; nf < 2; ++nf) bfr[nf] = *(const bf16x8*)(Bb + nf*16*KP_ + ks);
    #pragma unroll
    for (int mf = 0; mf < 4; ++mf)
      #pragma unroll
      for (int nf = 0; nf < 2; ++nf)
        acc[mf][nf] = __builtin_amdgcn_mfma_f32_16x16x32_bf16(a[mf], bfr[nf], acc[mf][nf], 0, 0, 0);
  }
  #pragma unroll
  for (int mf = 0; mf < 4; ++mf)
    #pragma unroll
    for (int nf = 0; nf < 2; ++nf) {
      int col = bn + nf*16 + r;
      float bc = pb[col];
      #pragma unroll
      for (int rr = 0; rr < 4; ++rr) {
        int row = bm + mf*16 + g*4 + rr;
        out[((size_t)b*TU_ + row)*OUTD_ + col] = acc[mf][nf][rr] + bc;
      }
    }
}

__global__ void k_len(const int* __restrict__ len, float* __restrict__ out) {
  int t = threadIdx.x;
  if (t < B_) out[t] = (float)len[t];
}

extern "C" void kernel_launch(void* const* d_in, const int* in_sizes, int n_in,
                              void* d_out, int out_size, void* d_ws, size_t ws_size,
                              hipStream_t stream) {
  const float* mel     = (const float*)d_in[0];
  const int*   lengths = (const int*)  d_in[1];
  const float* ln_in_w = (const float*)d_in[2];
  const float* ln_in_b = (const float*)d_in[3];
  const float* wq      = (const float*)d_in[4];
  const float* bq      = (const float*)d_in[5];
  const float* wkv     = (const float*)d_in[6];
  const float* bkv     = (const float*)d_in[7];
  const float* wo      = (const float*)d_in[8];
  const float* bo      = (const float*)d_in[9];
  const float* ln_ff_w = (const float*)d_in[10];
  const float* ln_ff_b = (const float*)d_in[11];
  const float* w1      = (const float*)d_in[12];
  const float* b1      = (const float*)d_in[13];
  const float* w2      = (const float*)d_in[14];
  const float* b2      = (const float*)d_in[15];
  const float* ln_o_w  = (const float*)d_in[16];
  const float* ln_o_b  = (const float*)d_in[17];
  const float* pw      = (const float*)d_in[18];
  const float* pb      = (const float*)d_in[19];
  float* out = (float*)d_out;

  // ---- workspace (fp32 first, then bf16; all 16B-aligned sizes) ----
  float* ws = (float*)d_ws;
  float* x     = ws; ws += NR_*D_;
  float* qb    = ws; ws += NR_*D_;
  float* kvb   = ws; ws += NR_*2*D_;
  float* resb  = ws; ws += NR_*D_;
  float* bqkv  = ws; ws += NLAYERS_*240;
  ushort_t* us = (ushort_t*)ws;
  ushort_t* xnbf  = us; us += NR_*KP_;
  ushort_t* attbf = us; us += NR_*KP_;
  ushort_t* hnbf  = us; us += NR_*KP_;
  ushort_t* ff1bf = us; us += NR_*FFN_;
  ushort_t* w1T   = us; us += S1_;
  ushort_t* w2T   = us; us += S2_;
  ushort_t* wqkvT = us; us += S3_;
  ushort_t* woT   = us; us += S4_;
  ushort_t* pwT   = us; us += S5_;

  k_wprep<<<(WPREP_N_ + 255)/256, 256, 0, stream>>>(w1, w2, wq, wkv, wo, pw, bq, bkv,
                                                    w1T, w2T, wqkvT, woT, pwT, bqkv);
  k_build_ln<<<NR_, 128, 0, stream>>>(mel, ln_in_w, ln_in_b, x, xnbf);

  for (int l = 0; l < NLAYERS_; ++l) {
    k_qkv_mfma<<<dim3(NR_/64, 2), 256, 0, stream>>>(xnbf, wqkvT + l*256*KP_,
                                                    bqkv + l*240, qb, kvb);
    k_attn<<<dim3(NSEG_, B_, H_), 256, 0, stream>>>(qb, kvb, attbf);
    k_wo_res_ln<<<NR_/16, 64, 0, stream>>>(attbf, woT + l*D_*KP_, bo + l*D_, x, resb,
                                           ln_ff_w + l*D_, ln_ff_b + l*D_, hnbf);
    k_ffn1_mfma<<<dim3(NR_/64, FFN_/128), 256, 0, stream>>>(hnbf, w1T + l*FFN_*KP_,
                                                            b1 + l*FFN_, ff1bf);
    int last = (l == NLAYERS_-1);
    k_ffn2_fused<<<NR_/16, 512, 0, stream>>>(ff1bf, w2T + l*D_*FFN_, b2 + l*D_, resb,
                                             ln_o_w + l*D_, ln_o_b + l*D_,
                                             ln_in_w + (last ? 0 : (l+1)*D_),
                                             ln_in_b + (last ? 0 : (l+1)*D_),
                                             last, x, xnbf);
  }

  k_proj_mfma<<<dim3(TU_/64, OUTD_/128, B_), 256, 0, stream>>>(xnbf, pwT, pb, out);
  k_len<<<1, 64, 0, stream>>>(lengths, out + (size_t)B_*TU_*OUTD_);
}